// Round 1
// baseline (330.164 us; speedup 1.0000x reference)
//
#include <hip/hip_runtime.h>
#include <math.h>

// Problem constants (fixed by reference setup_inputs)
constexpr int B = 32;
constexpr int L = 8;
constexpr int P = 1024;
constexpr int S = 1023;          // segments per lane
constexpr float EPS = 1e-8f;

#define INV8PI 0.039788735772973836  // 1/(8*pi)
#define INV2PI 0.15915494309189535   // 1/(2*pi)

// seg = {dlx, dly, midx, midy}, faithful to reference:
// diff = p[i+1]-p[i]; scale = sqrt(s2)/sqrt(s2+eps); dl = diff*scale; mid = avg
__device__ __forceinline__ float4 make_seg(const float2* __restrict__ pts, int i) {
    float2 a = pts[i];
    float2 b = pts[i + 1];
    float dx = b.x - a.x, dy = b.y - a.y;
    float s2 = dx * dx + dy * dy;
    float len = sqrtf(s2);
    float scale = len / sqrtf(s2 + EPS);
    float4 r;
    r.x = dx * scale;
    r.y = dy * scale;
    r.z = 0.5f * (a.x + b.x);
    r.w = 0.5f * (a.y + b.y);
    return r;
}

// grid: (12, 256). blockIdx.y = lane (b*L+l). blockIdx.x: mtype = x>>2 (0=PP,1=GG,2=PG),
// rtile = x&3 (rows [rtile*256, rtile*256+255]).
// Each thread owns one row segment (registers); all column segments staged in LDS.
__global__ __launch_bounds__(256, 4) void
pair_kernel(const float* __restrict__ pred, const float* __restrict__ gt,
            double* __restrict__ acc) {
    __shared__ float4 cs[1024];      // column segments (16 KB)
    __shared__ double wsum[4];

    const int lane  = blockIdx.y;
    const int part  = blockIdx.x;
    const int mtype = part >> 2;     // 0: pred-pred, 1: gt-gt, 2: pred-gt
    const int rtile = part & 3;
    const int tid   = threadIdx.x;

    const float2* rowpts = (const float2*)(mtype == 1 ? gt : pred) + (size_t)lane * P;
    const float2* colpts = (const float2*)(mtype == 0 ? pred : gt) + (size_t)lane * P;

    // stage column segments into LDS (coalesced global reads, 1023 segs)
    for (int j = tid; j < S; j += 256) {
        cs[j] = make_seg(colpts, j);
    }

    // this thread's row segment
    const int i = rtile * 256 + tid;
    float4 rs;
    if (i < S) {
        rs = make_seg(rowpts, i);
    } else {
        rs.x = 0.f; rs.y = 0.f; rs.z = 0.f; rs.w = 0.f;  // dot=0 -> contributes 0
    }
    __syncthreads();

    double accd = 0.0;

    // line term: sum |dl| (once per lane per curve; coefficient 1/(8pi) matches self blocks)
    if (mtype < 2 && rtile == 0) {
        float lf = 0.0f;
        for (int j = tid; j < S; j += 256) {
            float4 s = cs[j];
            lf += sqrtf(s.x * s.x + s.y * s.y);
        }
        accd += (double)lf;
    }

    const int jstart = (mtype == 2) ? 0 : (rtile * 256 + 1);

    // pair loop, chunked so float accumulator stays short (precision)
    for (int j0 = jstart; j0 < S; j0 += 256) {
        const int je = (j0 + 256 < S) ? (j0 + 256) : S;
        float accf = 0.0f;
#pragma unroll 4
        for (int j = j0; j < je; ++j) {
            float4 c = cs[j];                       // uniform address -> LDS broadcast
            float dot = rs.x * c.x + rs.y * c.y;
            float rdx = c.z - rs.z;
            float rdy = c.w - rs.w;
            float d2  = rdx * rdx + rdy * rdy;
            float r   = __builtin_amdgcn_sqrtf(d2) + EPS;
            float t   = dot * __builtin_amdgcn_rcpf(r);
            if (mtype != 2) t = (j > i) ? t : 0.0f; // triangular mask (uniform branch, per-lane select)
            accf += t;
        }
        accd += (double)accf;
    }

    // wave reduce (64 lanes), then cross-wave via LDS, one double atomic per block
    for (int off = 32; off; off >>= 1) accd += __shfl_down(accd, off, 64);
    if ((tid & 63) == 0) wsum[tid >> 6] = accd;
    __syncthreads();
    if (tid == 0) {
        double tot = wsum[0] + wsum[1] + wsum[2] + wsum[3];
        double coef = (mtype == 2) ? INV2PI : INV8PI;
        // loss = line_p + line_g + sum_PP dot/(8 pi r) + sum_GG dot/(8 pi r) + sum_PG dot/(2 pi r)
        atomicAdd(acc, tot * coef);
    }
}

__global__ void finalize_kernel(const double* __restrict__ acc, float* __restrict__ out) {
    out[0] = (float)(acc[0] / (double)B);
}

extern "C" void kernel_launch(void* const* d_in, const int* in_sizes, int n_in,
                              void* d_out, int out_size, void* d_ws, size_t ws_size,
                              hipStream_t stream) {
    const float* pred = (const float*)d_in[0];
    const float* gt   = (const float*)d_in[1];
    double* acc = (double*)d_ws;

    hipMemsetAsync(d_ws, 0, sizeof(double), stream);

    dim3 grid(12, 256);
    pair_kernel<<<grid, dim3(256), 0, stream>>>(pred, gt, acc);
    finalize_kernel<<<1, 1, 0, stream>>>(acc, (float*)d_out);
}

// Round 4
// 224.008 us; speedup vs baseline: 1.4739x; 1.4739x over previous
//
#include <hip/hip_runtime.h>
#include <math.h>

// Problem constants (fixed by reference setup_inputs)
constexpr int B = 32;
constexpr int L = 8;
constexpr int P = 1024;
constexpr int S = 1023;          // segments per lane
constexpr float EPS = 1e-8f;

#define INV8PI 0.039788735772973836  // 1/(8*pi)
#define INV2PI 0.15915494309189535   // 1/(2*pi)

// seg = {dlx, dly, midx, midy}, faithful to reference:
// diff = p[i+1]-p[i]; scale = sqrt(s2)/sqrt(s2+eps); dl = diff*scale; mid = avg
__device__ __forceinline__ float4 make_seg(const float2* __restrict__ pts, int i) {
    float2 a = pts[i];
    float2 b = pts[i + 1];
    float dx = b.x - a.x, dy = b.y - a.y;
    float s2 = dx * dx + dy * dy;
    float len = sqrtf(s2);
    float scale = len / sqrtf(s2 + EPS);
    float4 r;
    r.x = dx * scale;
    r.y = dy * scale;
    r.z = 0.5f * (a.x + b.x);
    r.w = 0.5f * (a.y + b.y);
    return r;
}

// t = dot(dl_i, dl_j) * rsqrt(|mid_i-mid_j|^2).
// 1e-30 seeded in the innermost fma addend: free NaN-proofing (d2 >= 1e-30),
// never changes results at fp32 precision for d2 >= ~1e-23.
__device__ __forceinline__ float pair_term(float rx, float ry, float mz, float mw,
                                           const float4& c) {
    float rdx = c.z - mz;
    float rdy = c.w - mw;
    float d2  = fmaf(rdx, rdx, fmaf(rdy, rdy, 1e-30f));
    float dot = fmaf(rx, c.x, ry * c.y);
    return dot * __builtin_amdgcn_rsqf(d2);
}

// grid: (12, 256). blockIdx.y = lane (b*L+l). blockIdx.x: mtype = x>>2 (0=PP,1=GG,2=PG),
// rtile = x&3 (rows [rtile*256, rtile*256+255]).
// Each thread owns one row segment (registers); all column segments staged in LDS.
__global__ __launch_bounds__(256, 8) void
pair_kernel(const float* __restrict__ pred, const float* __restrict__ gt,
            double* __restrict__ acc) {
    __shared__ float4 cs[1024];      // column segments (16 KB)
    __shared__ double wsum[4];

    const int lane  = blockIdx.y;
    const int part  = blockIdx.x;
    const int mtype = part >> 2;     // 0: pred-pred, 1: gt-gt, 2: pred-gt
    const int rtile = part & 3;
    const int tid   = threadIdx.x;

    const float2* rowpts = (const float2*)(mtype == 1 ? gt : pred) + (size_t)lane * P;
    const float2* colpts = (const float2*)(mtype == 0 ? pred : gt) + (size_t)lane * P;

    // stage column segments into LDS (coalesced global reads, 1023 segs)
    for (int j = tid; j < S; j += 256) {
        cs[j] = make_seg(colpts, j);
    }

    // this thread's row segment
    const int i = rtile * 256 + tid;
    float4 rs;
    if (i < S) {
        rs = make_seg(rowpts, i);
    } else {
        rs.x = 0.f; rs.y = 0.f; rs.z = 0.f; rs.w = 0.f;  // dot=0 -> contributes 0
    }
    __syncthreads();

    const float rx = rs.x, ry = rs.y, mz = rs.z, mw = rs.w;

    double accd = 0.0;

    // line term: sum |dl| (once per lane per curve; coefficient 1/(8pi) matches self blocks)
    if (mtype < 2 && rtile == 0) {
        float lf = 0.0f;
        for (int j = tid; j < S; j += 256) {
            float4 s = cs[j];
            lf += sqrtf(s.x * s.x + s.y * s.y);
        }
        accd += (double)lf;
    }

    int jmain;
    if (mtype == 2) {
        jmain = 0;                    // full rectangular, no mask
    } else {
        // diagonal 64-wide chunk: wave-uniform start (i & ~63), per-lane mask j > i
        const int ws = i & ~63;
        const int je = (ws + 64 < S) ? (ws + 64) : S;
        float pf = 0.0f;
        for (int j = ws; j < je; ++j) {
            float t = pair_term(rx, ry, mz, mw, cs[j]);
            pf += (j > i) ? t : 0.0f;
        }
        accd += (double)pf;
        jmain = ws + 64;              // unmasked from next chunk on
    }

    // main unmasked pair loop, chunked so float accumulator stays short (precision)
    for (int j0 = jmain; j0 < S; j0 += 256) {
        const int je = (j0 + 256 < S) ? (j0 + 256) : S;
        float accf = 0.0f;
#pragma unroll 4
        for (int j = j0; j < je; ++j) {
            accf += pair_term(rx, ry, mz, mw, cs[j]);   // uniform LDS addr -> broadcast
        }
        accd += (double)accf;
    }

    // wave reduce (64 lanes), then cross-wave via LDS, one double atomic per block
    for (int off = 32; off; off >>= 1) accd += __shfl_down(accd, off, 64);
    if ((tid & 63) == 0) wsum[tid >> 6] = accd;
    __syncthreads();
    if (tid == 0) {
        double tot = wsum[0] + wsum[1] + wsum[2] + wsum[3];
        double coef = (mtype == 2) ? INV2PI : INV8PI;
        // loss = line_p + line_g + sum_PP dot/(8 pi r) + sum_GG dot/(8 pi r) + sum_PG dot/(2 pi r)
        atomicAdd(acc, tot * coef);
    }
}

__global__ void finalize_kernel(const double* __restrict__ acc, float* __restrict__ out) {
    out[0] = (float)(acc[0] / (double)B);
}

extern "C" void kernel_launch(void* const* d_in, const int* in_sizes, int n_in,
                              void* d_out, int out_size, void* d_ws, size_t ws_size,
                              hipStream_t stream) {
    const float* pred = (const float*)d_in[0];
    const float* gt   = (const float*)d_in[1];
    double* acc = (double*)d_ws;

    hipMemsetAsync(d_ws, 0, sizeof(double), stream);

    dim3 grid(12, 256);
    pair_kernel<<<grid, dim3(256), 0, stream>>>(pred, gt, acc);
    finalize_kernel<<<1, 1, 0, stream>>>(acc, (float*)d_out);
}